// Round 1
// baseline (569.787 us; speedup 1.0000x reference)
//
#include <hip/hip_runtime.h>
#include <math.h>

#define L_ 2048
#define D_ 512
#define K_ 64

enum { EPI_BIAS=0, EPI_GELU=1, EPI_AMP=2, EPI_PHASE=3, EPI_OUT=4 };

// C[M,N] = epi(A[M,Kd] @ W[Kd,N] + bias), tiles 64x64, BK=16, 256 thr, 4x4/thread
template<int EPI>
__global__ __launch_bounds__(256)
void gemm_k(const float* __restrict__ A, const float* __restrict__ W,
            const float* __restrict__ bias, float* __restrict__ C,
            int M, int N, int Kd,
            const float* __restrict__ extra, float* __restrict__ out2)
{
    __shared__ float4 As4[16][16];   // [k][m/4], transposed A tile
    __shared__ float4 Ws4[16][16];   // [k][n/4]
    float* As = (float*)As4;

    const int t  = threadIdx.x;
    const int tx = t & 15, ty = t >> 4;
    const int m0 = blockIdx.y * 64, n0 = blockIdx.x * 64;

    float acc[4][4] = {};

    const int ar = t >> 2;          // A tile row 0..63
    const int ak = (t & 3) << 2;    // A k-chunk 0,4,8,12
    const int wk = t >> 4;          // W tile k-row 0..15

    for (int k0 = 0; k0 < Kd; k0 += 16) {
        float4 av = *(const float4*)&A[(size_t)(m0 + ar) * Kd + k0 + ak];
        float4 wv = *(const float4*)&W[(size_t)(k0 + wk) * N + n0 + (tx << 2)];
        __syncthreads();
        As[(ak + 0) * 64 + ar] = av.x;
        As[(ak + 1) * 64 + ar] = av.y;
        As[(ak + 2) * 64 + ar] = av.z;
        As[(ak + 3) * 64 + ar] = av.w;
        Ws4[wk][tx] = wv;
        __syncthreads();
#pragma unroll
        for (int kk = 0; kk < 16; kk++) {
            float4 a = As4[kk][ty];
            float4 b = Ws4[kk][tx];
            float aa[4] = {a.x, a.y, a.z, a.w};
            float bb[4] = {b.x, b.y, b.z, b.w};
#pragma unroll
            for (int i = 0; i < 4; i++)
#pragma unroll
                for (int j = 0; j < 4; j++)
                    acc[i][j] += aa[i] * bb[j];
        }
    }

    const int nc = n0 + (tx << 2);
    float4 bv = *(const float4*)&bias[nc];
    const float bb4[4] = {bv.x, bv.y, bv.z, bv.w};

#pragma unroll
    for (int i = 0; i < 4; i++) {
        const int m = m0 + (ty << 2) + i;
        float v[4];
#pragma unroll
        for (int j = 0; j < 4; j++) v[j] = acc[i][j] + bb4[j];

        if (EPI == EPI_PHASE) {
            float4 am = *(const float4*)&extra[(size_t)m * N + nc];
            float amv[4] = {am.x, am.y, am.z, am.w};
            float vr[4], vi[4];
#pragma unroll
            for (int j = 0; j < 4; j++) {
                float p = tanhf(v[j]) * 3.14159265358979323846f;
                float sp, cp;
                sincosf(p, &sp, &cp);
                vr[j] = amv[j] * cp;
                vi[j] = amv[j] * sp;
            }
            *(float4*)&C[(size_t)m * N + nc]    = make_float4(vr[0], vr[1], vr[2], vr[3]);
            *(float4*)&out2[(size_t)m * N + nc] = make_float4(vi[0], vi[1], vi[2], vi[3]);
        } else {
            if (EPI == EPI_GELU) {
#pragma unroll
                for (int j = 0; j < 4; j++)
                    v[j] = 0.5f * v[j] * (1.0f + erff(v[j] * 0.70710678118654752f));
            } else if (EPI == EPI_AMP) {
#pragma unroll
                for (int j = 0; j < 4; j++) {
                    float u = v[j];
                    u = (u > 20.f) ? u : log1pf(expf(u));
                    v[j] = u + 0.1f;
                }
            } else if (EPI == EPI_OUT) {
                float4 xv = *(const float4*)&extra[(size_t)m * N + nc];
                v[0] += xv.x; v[1] += xv.y; v[2] += xv.z; v[3] += xv.w;
            }
            *(float4*)&C[(size_t)m * N + nc] = make_float4(v[0], v[1], v[2], v[3]);
        }
    }
}

// Causal attention: retrieved[l,d] = sum_{t<=l} S[l,t] V[t,d]
// block = (t-group g, l-tile lt). 32 l-rows x full D=512. Partials into P[g].
__global__ __launch_bounds__(256)
void att_k(const float* __restrict__ qr, const float* __restrict__ qi,
           const float* __restrict__ kr, const float* __restrict__ ki,
           const float* __restrict__ V, float* __restrict__ P, int ngroups)
{
    __shared__ __align__(16) float qs[32][128];
    __shared__ __align__(16) float ks[32][128];
    __shared__ __align__(16) float Ss[32][36];

    const int t  = threadIdx.x;
    const int lt = blockIdx.y, g = blockIdx.x;
    const int l0 = lt * 32;

    {   // stage q phasors (qr | qi) for this block's 32 rows
        const int row = t >> 5;            // 0..7
        const int c4  = (t & 31) << 2;     // 0..124
#pragma unroll
        for (int r0 = 0; r0 < 32; r0 += 8) {
            const int rr = r0 + row;
            const float* src = (c4 < 64) ? &qr[(size_t)(l0 + rr) * 64 + c4]
                                         : &qi[(size_t)(l0 + rr) * 64 + (c4 - 64)];
            *(float4*)&qs[rr][c4] = *(const float4*)src;
        }
    }

    float accx[32], accy[32];
#pragma unroll
    for (int i = 0; i < 32; i++) { accx[i] = 0.f; accy[i] = 0.f; }

    const int sl  = t >> 3;         // S row 0..31
    const int stq = (t & 7) << 2;   // S col base 0..28

    for (int tile = g; tile <= lt; tile += ngroups) {
        const int t0 = tile * 32;
        __syncthreads();
        {   // stage k phasors for this t-tile
            const int row = t >> 5;
            const int c4  = (t & 31) << 2;
#pragma unroll
            for (int r0 = 0; r0 < 32; r0 += 8) {
                const int rr = r0 + row;
                const float* src = (c4 < 64) ? &kr[(size_t)(t0 + rr) * 64 + c4]
                                             : &ki[(size_t)(t0 + rr) * 64 + (c4 - 64)];
                *(float4*)&ks[rr][c4] = *(const float4*)src;
            }
        }
        __syncthreads();
        {   // S[sl][stq..stq+3] = q[sl] . k[stq+r] over 128
            float s[4] = {0.f, 0.f, 0.f, 0.f};
            const float4* qv  = (const float4*)qs[sl];
            const float4* k0v = (const float4*)ks[stq + 0];
            const float4* k1v = (const float4*)ks[stq + 1];
            const float4* k2v = (const float4*)ks[stq + 2];
            const float4* k3v = (const float4*)ks[stq + 3];
#pragma unroll 8
            for (int c = 0; c < 32; c++) {
                float4 q = qv[c];
                float4 a = k0v[c]; s[0] += q.x*a.x + q.y*a.y + q.z*a.z + q.w*a.w;
                float4 b = k1v[c]; s[1] += q.x*b.x + q.y*b.y + q.z*b.z + q.w*b.w;
                float4 cc= k2v[c]; s[2] += q.x*cc.x+ q.y*cc.y+ q.z*cc.z+ q.w*cc.w;
                float4 d = k3v[c]; s[3] += q.x*d.x + q.y*d.y + q.z*d.z + q.w*d.w;
            }
            const int lg = l0 + sl;
#pragma unroll
            for (int r = 0; r < 4; r++)
                Ss[sl][stq + r] = (t0 + stq + r <= lg) ? s[r] : 0.f;
        }
        __syncthreads();
        {   // acc[l] += S[l][tt] * V[t0+tt][2t..2t+1]
            float2 v[32];
            const float2* Vp = (const float2*)V;
#pragma unroll
            for (int tt = 0; tt < 32; tt++)
                v[tt] = Vp[(size_t)(t0 + tt) * 256 + t];
#pragma unroll
            for (int l = 0; l < 32; l++) {
                const float4* srow = (const float4*)Ss[l];
                float ax = accx[l], ay = accy[l];
#pragma unroll
                for (int c = 0; c < 8; c++) {
                    float4 s4 = srow[c];
                    float2 v0 = v[4*c], v1 = v[4*c+1], v2 = v[4*c+2], v3 = v[4*c+3];
                    ax += s4.x * v0.x; ay += s4.x * v0.y;
                    ax += s4.y * v1.x; ay += s4.y * v1.y;
                    ax += s4.z * v2.x; ay += s4.z * v2.y;
                    ax += s4.w * v3.x; ay += s4.w * v3.y;
                }
                accx[l] = ax; accy[l] = ay;
            }
        }
    }

    float2* Pp = (float2*)P;
#pragma unroll
    for (int l = 0; l < 32; l++)
        Pp[((size_t)g * L_ + l0 + l) * 256 + t] = make_float2(accx[l], accy[l]);
}

// reduce partials, scale by 1/sqrt((l+1)K), LayerNorm -> rn
__global__ __launch_bounds__(256)
void reduce_ln_k(const float* __restrict__ P, int ng,
                 const float* __restrict__ lng, const float* __restrict__ lnb,
                 float* __restrict__ rn)
{
    const int l = blockIdx.x, t = threadIdx.x;
    const float2* Pp = (const float2*)P;
    float2 r = make_float2(0.f, 0.f);
    for (int gi = 0; gi < ng; gi++) {
        float2 p = Pp[((size_t)gi * L_ + l) * 256 + t];
        r.x += p.x; r.y += p.y;
    }
    const float scale = rsqrtf((float)((l + 1) * K_));
    r.x *= scale; r.y *= scale;

    float s = r.x + r.y, s2 = r.x * r.x + r.y * r.y;
    __shared__ float sb[8];
#pragma unroll
    for (int o = 32; o > 0; o >>= 1) {
        s  += __shfl_down(s,  o);
        s2 += __shfl_down(s2, o);
    }
    if ((t & 63) == 0) { int w = t >> 6; sb[w] = s; sb[4 + w] = s2; }
    __syncthreads();
    s  = sb[0] + sb[1] + sb[2] + sb[3];
    s2 = sb[4] + sb[5] + sb[6] + sb[7];

    const float mu   = s * (1.f / 512.f);
    const float var  = s2 * (1.f / 512.f) - mu * mu;
    const float rstd = rsqrtf(var + 1e-5f);

    const int d = t << 1;
    rn[(size_t)l * 512 + d]     = (r.x - mu) * rstd * lng[d]     + lnb[d];
    rn[(size_t)l * 512 + d + 1] = (r.y - mu) * rstd * lng[d + 1] + lnb[d + 1];
}

extern "C" void kernel_launch(void* const* d_in, const int* in_sizes, int n_in,
                              void* d_out, int out_size, void* d_ws, size_t ws_size,
                              hipStream_t stream)
{
    const float* x     = (const float*)d_in[0];
    const float* ke_w1 = (const float*)d_in[1];
    const float* ke_b1 = (const float*)d_in[2];
    const float* ke_w2 = (const float*)d_in[3];
    const float* ke_b2 = (const float*)d_in[4];
    const float* qe_w1 = (const float*)d_in[5];
    const float* qe_b1 = (const float*)d_in[6];
    const float* qe_w2 = (const float*)d_in[7];
    const float* qe_b2 = (const float*)d_in[8];
    const float* amp_w = (const float*)d_in[9];
    const float* amp_b = (const float*)d_in[10];
    const float* v_w   = (const float*)d_in[11];
    const float* v_b   = (const float*)d_in[12];
    const float* ln_g  = (const float*)d_in[13];
    const float* ln_b  = (const float*)d_in[14];
    const float* out_w = (const float*)d_in[15];
    const float* out_b = (const float*)d_in[16];
    float* out = (float*)d_out;
    float* ws  = (float*)d_ws;

    float* hk  = ws;                 // 1048576
    float* hq  = ws + 1048576;       // 1048576
    float* V   = ws + 2097152;       // 1048576
    float* rn  = ws + 3145728;       // 1048576
    float* amp = ws + 4194304;       // 131072
    float* kr  = ws + 4325376;
    float* ki  = ws + 4456448;
    float* qr  = ws + 4587520;
    float* qi  = ws + 4718592;
    float* P   = ws + 4849664;       // ng * 1048576

    const size_t base_bytes = 4849664ull * 4ull;
    const size_t per_group  = 1048576ull * 4ull;
    int ng = 1;
    if (ws_size > base_bytes + per_group) {
        size_t n = (ws_size - base_bytes) / per_group;
        ng = (n > 8) ? 8 : (int)n;
        if (ng < 1) ng = 1;
    }

    dim3 blk(256);
    gemm_k<EPI_GELU><<<dim3(8, 32), blk, 0, stream>>>(x, ke_w1, ke_b1, hk, L_, D_, D_, nullptr, nullptr);
    gemm_k<EPI_GELU><<<dim3(8, 32), blk, 0, stream>>>(x, qe_w1, qe_b1, hq, L_, D_, D_, nullptr, nullptr);
    gemm_k<EPI_BIAS><<<dim3(8, 32), blk, 0, stream>>>(x, v_w, v_b, V, L_, D_, D_, nullptr, nullptr);
    gemm_k<EPI_AMP><<<dim3(1, 32), blk, 0, stream>>>(x, amp_w, amp_b, amp, L_, K_, D_, nullptr, nullptr);
    gemm_k<EPI_PHASE><<<dim3(1, 32), blk, 0, stream>>>(hk, ke_w2, ke_b2, kr, L_, K_, D_, amp, ki);
    gemm_k<EPI_PHASE><<<dim3(1, 32), blk, 0, stream>>>(hq, qe_w2, qe_b2, qr, L_, K_, D_, amp, qi);
    att_k<<<dim3(ng, L_ / 32), blk, 0, stream>>>(qr, qi, kr, ki, V, P, ng);
    reduce_ln_k<<<dim3(L_), blk, 0, stream>>>(P, ng, ln_g, ln_b, rn);
    gemm_k<EPI_OUT><<<dim3(8, 32), blk, 0, stream>>>(rn, out_w, out_b, out, L_, D_, D_, x, nullptr);
}

// Round 2
// 188.196 us; speedup vs baseline: 3.0276x; 3.0276x over previous
//
#include <hip/hip_runtime.h>
#include <math.h>

#define L_ 2048
#define D_ 512
#define K_ 64

typedef __attribute__((ext_vector_type(8))) short short8;
typedef __attribute__((ext_vector_type(4))) float f32x4;
typedef __attribute__((ext_vector_type(4))) unsigned short us4;

__device__ __forceinline__ unsigned short f2bf(float f) {
    unsigned int u = __builtin_bit_cast(unsigned int, f);
    u += 0x7fffu + ((u >> 16) & 1u);   // RNE
    return (unsigned short)(u >> 16);
}

__device__ __forceinline__ f32x4 MFMA(short8 a, short8 b, f32x4 c) {
    return __builtin_amdgcn_mfma_f32_16x16x32_bf16(a, b, c, 0, 0, 0);
}

// ---------- cast x fp32 -> bf16 ----------
__global__ __launch_bounds__(256)
void cast_x_k(const float* __restrict__ x, unsigned short* __restrict__ xb) {
    int i = blockIdx.x * 256 + threadIdx.x;     // 262144 threads, 4 elems each
    float4 v = ((const float4*)x)[i];
    us4 o;
    o.x = f2bf(v.x); o.y = f2bf(v.y); o.z = f2bf(v.z); o.w = f2bf(v.w);
    *(us4*)&xb[(size_t)i * 4] = o;
}

// ---------- transpose+cast all weights: src [R][C] fp32 -> dst [C][R] bf16 ----------
__global__ __launch_bounds__(256)
void transw_k(const float* s0, const float* s1, const float* s2, const float* s3,
              const float* s4, const float* s5, const float* s6,
              unsigned short* d0, unsigned short* d1, unsigned short* d2, unsigned short* d3,
              unsigned short* d4, unsigned short* d5, unsigned short* d6)
{
    const float* S; unsigned short* D; int C;   // R=512 always
    switch (blockIdx.z) {
        case 0: S = s0; D = d0; C = 512; break;
        case 1: S = s1; D = d1; C = 512; break;
        case 2: S = s2; D = d2; C = 512; break;
        case 3: S = s3; D = d3; C = 512; break;
        case 4: S = s4; D = d4; C = 64;  break;
        case 5: S = s5; D = d5; C = 64;  break;
        default: S = s6; D = d6; C = 64; break;
    }
    const int R = 512;
    int c0 = blockIdx.x * 32, r0 = blockIdx.y * 32;
    if (c0 >= C) return;
    __shared__ float tile[32][33];
    int t = threadIdx.x, r = t >> 3, c4 = (t & 7) * 4;
    float4 v = *(const float4*)&S[(size_t)(r0 + r) * C + c0 + c4];
    tile[r][c4 + 0] = v.x; tile[r][c4 + 1] = v.y;
    tile[r][c4 + 2] = v.z; tile[r][c4 + 3] = v.w;
    __syncthreads();
    us4 o;
    o.x = f2bf(tile[c4 + 0][r]); o.y = f2bf(tile[c4 + 1][r]);
    o.z = f2bf(tile[c4 + 2][r]); o.w = f2bf(tile[c4 + 3][r]);
    *(us4*)&D[(size_t)(c0 + r) * R + r0 + c4] = o;
}

// ---------- transpose V bf16 [2048][512] -> Vt [512][2048] ----------
__global__ __launch_bounds__(256)
void transv_k(const unsigned short* __restrict__ Vb, unsigned short* __restrict__ Vt)
{
    __shared__ unsigned short tile[32][33];
    int c0 = blockIdx.x * 32, r0 = blockIdx.y * 32;
    int t = threadIdx.x, r = t >> 3, c4 = (t & 7) * 4;
    us4 v = *(const us4*)&Vb[(size_t)(r0 + r) * 512 + c0 + c4];
    tile[r][c4 + 0] = v.x; tile[r][c4 + 1] = v.y;
    tile[r][c4 + 2] = v.z; tile[r][c4 + 3] = v.w;
    __syncthreads();
    us4 o;
    o.x = tile[c4 + 0][r]; o.y = tile[c4 + 1][r];
    o.z = tile[c4 + 2][r]; o.w = tile[c4 + 3][r];
    *(us4*)&Vt[(size_t)(c0 + r) * 2048 + r0 + c4] = o;
}

// ---------- bf16 MFMA GEMM: C = epi(A[M,Kd] @ Bt[N,Kd]^T + bias) ----------
enum { EPI_BIAS = 0, EPI_GELU = 1, EPI_AMP = 2, EPI_PHASE = 3, EPI_OUT = 4 };

template<int EPI>
__global__ __launch_bounds__(256)
void mgemm_k(const unsigned short* __restrict__ A, const unsigned short* __restrict__ Bt,
             const float* __restrict__ bias, int M, int N, int Kd,
             unsigned short* __restrict__ Cb, float* __restrict__ Cf,
             const float* __restrict__ extra)
{
    __shared__ unsigned short As[64 * 72];
    __shared__ unsigned short Bs[64 * 72];

    const int t = threadIdx.x;
    const int m0 = blockIdx.y * 64, n0 = blockIdx.x * 64;
    const int w = t >> 6, lane = t & 63, n_ = lane & 15, quad = lane >> 4;
    const int mh = (w >> 1) * 32, nh = (w & 1) * 32;

    f32x4 acc[2][2];
#pragma unroll
    for (int i = 0; i < 2; i++)
#pragma unroll
        for (int j = 0; j < 2; j++) acc[i][j] = (f32x4){0.f, 0.f, 0.f, 0.f};

    const int sr = t >> 2, sseg = (t & 3) * 16;
    const unsigned short* Ap = &A[(size_t)(m0 + sr) * Kd + sseg];
    const unsigned short* Bp = &Bt[(size_t)(n0 + sr) * Kd + sseg];
    unsigned short* Asw = &As[sr * 72 + sseg];
    unsigned short* Bsw = &Bs[sr * 72 + sseg];

    for (int k0 = 0; k0 < Kd; k0 += 64) {
        short8 av0 = *(const short8*)(Ap + k0);
        short8 av1 = *(const short8*)(Ap + k0 + 8);
        short8 bv0 = *(const short8*)(Bp + k0);
        short8 bv1 = *(const short8*)(Bp + k0 + 8);
        __syncthreads();
        *(short8*)(Asw)     = av0; *(short8*)(Asw + 8) = av1;
        *(short8*)(Bsw)     = bv0; *(short8*)(Bsw + 8) = bv1;
        __syncthreads();
#pragma unroll
        for (int kc = 0; kc < 2; kc++) {
            short8 a0 = *(const short8*)&As[(mh + n_) * 72 + kc * 32 + quad * 8];
            short8 a1 = *(const short8*)&As[(mh + 16 + n_) * 72 + kc * 32 + quad * 8];
            short8 b0 = *(const short8*)&Bs[(nh + n_) * 72 + kc * 32 + quad * 8];
            short8 b1 = *(const short8*)&Bs[(nh + 16 + n_) * 72 + kc * 32 + quad * 8];
            acc[0][0] = MFMA(a0, b0, acc[0][0]);
            acc[0][1] = MFMA(a0, b1, acc[0][1]);
            acc[1][0] = MFMA(a1, b0, acc[1][0]);
            acc[1][1] = MFMA(a1, b1, acc[1][1]);
        }
    }

#pragma unroll
    for (int i = 0; i < 2; i++) {
#pragma unroll
        for (int j = 0; j < 2; j++) {
            const int mb = m0 + mh + i * 16 + quad * 4;
            const int nb = n0 + nh + j * 16 + n_;
            const float bsv = bias[nb];
#pragma unroll
            for (int reg = 0; reg < 4; reg++) {
                const int m = mb + reg;
                float v = acc[i][j][reg] + bsv;
                if (EPI == EPI_GELU) {
                    v = 0.5f * v * (1.0f + erff(v * 0.70710678118654752f));
                    Cb[(size_t)m * N + nb] = f2bf(v);
                } else if (EPI == EPI_BIAS) {
                    Cb[(size_t)m * N + nb] = f2bf(v);
                } else if (EPI == EPI_AMP) {
                    float u = (v > 20.f) ? v : log1pf(expf(v));
                    Cf[(size_t)m * N + nb] = u + 0.1f;
                } else if (EPI == EPI_PHASE) {
                    float am = extra[(size_t)m * 64 + nb];
                    float p = tanhf(v) * 3.14159265358979323846f;
                    float sp, cp; sincosf(p, &sp, &cp);
                    Cb[(size_t)m * 128 + nb]      = f2bf(am * cp);
                    Cb[(size_t)m * 128 + 64 + nb] = f2bf(am * sp);
                } else { // EPI_OUT
                    Cf[(size_t)m * N + nb] = v + extra[(size_t)m * N + nb];
                }
            }
        }
    }
}

// ---------- MFMA causal attention ----------
// block (g, lt): 32 l-rows, full D=512. wave w: S-quarter (lh=w>>1, th=w&1), d-range w*128.
__global__ __launch_bounds__(256)
void attm_k(const unsigned short* __restrict__ Qp, const unsigned short* __restrict__ Kp,
            const unsigned short* __restrict__ Vt, float* __restrict__ P, int ng)
{
    __shared__ unsigned short Ss[32 * 56];

    const int t = threadIdx.x;
    const int g = blockIdx.x, lt = blockIdx.y;
    const int l0 = lt * 32;
    const int w = t >> 6, lane = t & 63, n_ = lane & 15, quad = lane >> 4;
    const int lh = (w >> 1) * 16, th = (w & 1) * 16;

    short8 qf[4];
    {
        const unsigned short* qrow = &Qp[(size_t)(l0 + lh + n_) * 128 + quad * 8];
#pragma unroll
        for (int kc = 0; kc < 4; kc++) qf[kc] = *(const short8*)(qrow + kc * 32);
    }

    f32x4 acc[2][8];
#pragma unroll
    for (int i = 0; i < 2; i++)
#pragma unroll
        for (int j = 0; j < 8; j++) acc[i][j] = (f32x4){0.f, 0.f, 0.f, 0.f};

    for (int tile = g; tile <= lt; tile += ng) {
        const int t0 = tile * 32;
        const unsigned short* krow = &Kp[(size_t)(t0 + th + n_) * 128 + quad * 8];
        f32x4 s = (f32x4){0.f, 0.f, 0.f, 0.f};
#pragma unroll
        for (int kc = 0; kc < 4; kc++)
            s = MFMA(qf[kc], *(const short8*)(krow + kc * 32), s);

        const int lrow = lh + quad * 4;
        if (tile == lt) {
            const int tg = t0 + th + n_;
#pragma unroll
            for (int reg = 0; reg < 4; reg++) {
                float v = (tg <= l0 + lrow + reg) ? s[reg] : 0.f;
                Ss[(lrow + reg) * 56 + th + n_] = f2bf(v);
            }
        } else {
#pragma unroll
            for (int reg = 0; reg < 4; reg++)
                Ss[(lrow + reg) * 56 + th + n_] = f2bf(s[reg]);
        }
        __syncthreads();

        short8 sa0 = *(const short8*)&Ss[n_ * 56 + quad * 8];
        short8 sa1 = *(const short8*)&Ss[(16 + n_) * 56 + quad * 8];
        const unsigned short* vrow = &Vt[(size_t)(w * 128 + n_) * 2048 + t0 + quad * 8];
#pragma unroll
        for (int jc = 0; jc < 8; jc++) {
            short8 vf = *(const short8*)(vrow + (size_t)jc * 16 * 2048);
            acc[0][jc] = MFMA(sa0, vf, acc[0][jc]);
            acc[1][jc] = MFMA(sa1, vf, acc[1][jc]);
        }
        __syncthreads();
    }

    float* Pg = &P[((size_t)g * L_ + l0) * 512];
#pragma unroll
    for (int i = 0; i < 2; i++) {
#pragma unroll
        for (int jc = 0; jc < 8; jc++) {
            const int row = i * 16 + quad * 4;
            const int d = w * 128 + jc * 16 + n_;
#pragma unroll
            for (int reg = 0; reg < 4; reg++)
                Pg[(size_t)(row + reg) * 512 + d] = acc[i][jc][reg];
        }
    }
}

// ---------- reduce partials, scale, LayerNorm -> rn (bf16) ----------
__global__ __launch_bounds__(256)
void reduce_ln_k(const float* __restrict__ P, int ng,
                 const float* __restrict__ lng, const float* __restrict__ lnb,
                 unsigned short* __restrict__ rnb)
{
    const int l = blockIdx.x, t = threadIdx.x;
    const float2* Pp = (const float2*)P;
    float2 r = make_float2(0.f, 0.f);
    for (int gi = 0; gi < ng; gi++) {
        float2 p = Pp[((size_t)gi * L_ + l) * 256 + t];
        r.x += p.x; r.y += p.y;
    }
    const float scale = rsqrtf((float)((l + 1) * K_));
    r.x *= scale; r.y *= scale;

    float s = r.x + r.y, s2 = r.x * r.x + r.y * r.y;
    __shared__ float sb[8];
#pragma unroll
    for (int o = 32; o > 0; o >>= 1) {
        s  += __shfl_down(s,  o);
        s2 += __shfl_down(s2, o);
    }
    if ((t & 63) == 0) { int wv = t >> 6; sb[wv] = s; sb[4 + wv] = s2; }
    __syncthreads();
    s  = sb[0] + sb[1] + sb[2] + sb[3];
    s2 = sb[4] + sb[5] + sb[6] + sb[7];

    const float mu   = s * (1.f / 512.f);
    const float var  = s2 * (1.f / 512.f) - mu * mu;
    const float rstd = rsqrtf(var + 1e-5f);

    const int d = t << 1;
    rnb[(size_t)l * 512 + d]     = f2bf((r.x - mu) * rstd * lng[d]     + lnb[d]);
    rnb[(size_t)l * 512 + d + 1] = f2bf((r.y - mu) * rstd * lng[d + 1] + lnb[d + 1]);
}

extern "C" void kernel_launch(void* const* d_in, const int* in_sizes, int n_in,
                              void* d_out, int out_size, void* d_ws, size_t ws_size,
                              hipStream_t stream)
{
    const float* x     = (const float*)d_in[0];
    const float* ke_w1 = (const float*)d_in[1];
    const float* ke_b1 = (const float*)d_in[2];
    const float* ke_w2 = (const float*)d_in[3];
    const float* ke_b2 = (const float*)d_in[4];
    const float* qe_w1 = (const float*)d_in[5];
    const float* qe_b1 = (const float*)d_in[6];
    const float* qe_w2 = (const float*)d_in[7];
    const float* qe_b2 = (const float*)d_in[8];
    const float* amp_w = (const float*)d_in[9];
    const float* amp_b = (const float*)d_in[10];
    const float* v_w   = (const float*)d_in[11];
    const float* v_b   = (const float*)d_in[12];
    const float* ln_g  = (const float*)d_in[13];
    const float* ln_b  = (const float*)d_in[14];
    const float* out_w = (const float*)d_in[15];
    const float* out_b = (const float*)d_in[16];
    float* out = (float*)d_out;
    char*  wsb = (char*)d_ws;

    // workspace layout (bytes)
    unsigned short* xb    = (unsigned short*)(wsb + 0);          // 2 MB
    unsigned short* hk    = (unsigned short*)(wsb + 2097152);    // 2 MB
    unsigned short* hq    = (unsigned short*)(wsb + 4194304);    // 2 MB
    unsigned short* Vb    = (unsigned short*)(wsb + 6291456);    // 2 MB
    unsigned short* Vt    = (unsigned short*)(wsb + 8388608);    // 2 MB
    unsigned short* Qp    = (unsigned short*)(wsb + 10485760);   // 0.5 MB
    unsigned short* Kp    = (unsigned short*)(wsb + 11010048);   // 0.5 MB
    float*          amp   = (float*)(wsb + 11534336);            // 0.5 MB
    unsigned short* rnb   = (unsigned short*)(wsb + 12058624);   // 2 MB
    unsigned short* wtke1 = (unsigned short*)(wsb + 14155776);
    unsigned short* wtqe1 = (unsigned short*)(wsb + 14680064);
    unsigned short* wtv   = (unsigned short*)(wsb + 15204352);
    unsigned short* wtout = (unsigned short*)(wsb + 15728640);
    unsigned short* wtke2 = (unsigned short*)(wsb + 16252928);
    unsigned short* wtqe2 = (unsigned short*)(wsb + 16318464);
    unsigned short* wtamp = (unsigned short*)(wsb + 16384000);
    float*          P     = (float*)(wsb + 16449536);            // ng * 4 MB

    const size_t base_bytes = 16449536ull;
    const size_t per_group  = 4194304ull;
    int ng = 1;
    if (ws_size > base_bytes + per_group) {
        size_t n = (ws_size - base_bytes) / per_group;
        ng = (n > 8) ? 8 : (int)n;
        if (ng < 1) ng = 1;
    }

    dim3 blk(256);
    cast_x_k<<<1024, blk, 0, stream>>>(x, xb);
    transw_k<<<dim3(16, 16, 7), blk, 0, stream>>>(ke_w1, qe_w1, v_w, out_w, ke_w2, qe_w2, amp_w,
                                                  wtke1, wtqe1, wtv, wtout, wtke2, wtqe2, wtamp);
    mgemm_k<EPI_GELU><<<dim3(8, 32), blk, 0, stream>>>(xb, wtke1, ke_b1, L_, D_, D_, hk, nullptr, nullptr);
    mgemm_k<EPI_GELU><<<dim3(8, 32), blk, 0, stream>>>(xb, wtqe1, qe_b1, L_, D_, D_, hq, nullptr, nullptr);
    mgemm_k<EPI_BIAS><<<dim3(8, 32), blk, 0, stream>>>(xb, wtv, v_b, L_, D_, D_, Vb, nullptr, nullptr);
    mgemm_k<EPI_AMP><<<dim3(1, 32), blk, 0, stream>>>(xb, wtamp, amp_b, L_, K_, D_, nullptr, amp, nullptr);
    mgemm_k<EPI_PHASE><<<dim3(1, 32), blk, 0, stream>>>(hk, wtke2, ke_b2, L_, K_, D_, Kp, nullptr, amp);
    mgemm_k<EPI_PHASE><<<dim3(1, 32), blk, 0, stream>>>(hq, wtqe2, qe_b2, L_, K_, D_, Qp, nullptr, amp);
    transv_k<<<dim3(16, 64), blk, 0, stream>>>(Vb, Vt);
    attm_k<<<dim3(ng, 64), blk, 0, stream>>>(Qp, Kp, Vt, P, ng);
    reduce_ln_k<<<dim3(L_), blk, 0, stream>>>(P, ng, ln_g, ln_b, rnb);
    mgemm_k<EPI_OUT><<<dim3(8, 32), blk, 0, stream>>>(rnb, wtout, out_b, L_, D_, D_, nullptr, out, x);
}

// Round 3
// 155.329 us; speedup vs baseline: 3.6683x; 1.2116x over previous
//
#include <hip/hip_runtime.h>
#include <math.h>

#define L_ 2048
#define D_ 512
#define K_ 64

typedef __attribute__((ext_vector_type(8))) short short8;
typedef __attribute__((ext_vector_type(4))) float f32x4;
typedef __attribute__((ext_vector_type(4))) unsigned short us4;

__device__ __forceinline__ unsigned short f2bf(float f) {
    unsigned int u = __builtin_bit_cast(unsigned int, f);
    u += 0x7fffu + ((u >> 16) & 1u);   // RNE
    return (unsigned short)(u >> 16);
}
__device__ __forceinline__ float bf2f(unsigned int u) {
    return __builtin_bit_cast(float, u << 16);
}
__device__ __forceinline__ f32x4 MFMA(short8 a, short8 b, f32x4 c) {
    return __builtin_amdgcn_mfma_f32_16x16x32_bf16(a, b, c, 0, 0, 0);
}

enum { EPI_BIAS = 0, EPI_GELU = 1, EPI_AMP = 2, EPI_PHASE = 3, EPI_OUT = 4 };

// ---------- pipelined bf16 MFMA GEMM body: 64x64 tile, BK=64, dbuf LDS ----------
template<int EPI>
__device__ __forceinline__ void gemm_body(
    const unsigned short* __restrict__ A, const unsigned short* __restrict__ Bt,
    const float* __restrict__ bias, int N, int Kd, int m0, int n0,
    unsigned short* __restrict__ Cb, float* __restrict__ Cf,
    const float* __restrict__ extra,
    unsigned short* As, unsigned short* Bs)      // each 2*64*72
{
    const int t = threadIdx.x;
    const int w = t >> 6, lane = t & 63, n_ = lane & 15, quad = lane >> 4;
    const int mh = (w >> 1) * 32, nh = (w & 1) * 32;

    f32x4 acc[2][2];
#pragma unroll
    for (int i = 0; i < 2; i++)
#pragma unroll
        for (int j = 0; j < 2; j++) acc[i][j] = (f32x4){0.f, 0.f, 0.f, 0.f};

    const int sr = t >> 2, sseg = (t & 3) * 16;
    const unsigned short* Ap = &A[(size_t)(m0 + sr) * Kd + sseg];
    const unsigned short* Bp = &Bt[(size_t)(n0 + sr) * Kd + sseg];
    const int swoff = sr * 72 + sseg;

    short8 av0 = *(const short8*)(Ap);
    short8 av1 = *(const short8*)(Ap + 8);
    short8 bv0 = *(const short8*)(Bp);
    short8 bv1 = *(const short8*)(Bp + 8);

    int buf = 0;
    *(short8*)(As + swoff) = av0; *(short8*)(As + swoff + 8) = av1;
    *(short8*)(Bs + swoff) = bv0; *(short8*)(Bs + swoff + 8) = bv1;
    __syncthreads();

    for (int k0 = 0; k0 < Kd; k0 += 64) {
        const bool more = (k0 + 64 < Kd);
        if (more) {
            av0 = *(const short8*)(Ap + k0 + 64);
            av1 = *(const short8*)(Ap + k0 + 72);
            bv0 = *(const short8*)(Bp + k0 + 64);
            bv1 = *(const short8*)(Bp + k0 + 72);
        }
        const unsigned short* Ab = As + buf * 4608;
        const unsigned short* Bb = Bs + buf * 4608;
#pragma unroll
        for (int kc = 0; kc < 2; kc++) {
            short8 a0 = *(const short8*)&Ab[(mh      + n_) * 72 + kc * 32 + quad * 8];
            short8 a1 = *(const short8*)&Ab[(mh + 16 + n_) * 72 + kc * 32 + quad * 8];
            short8 b0 = *(const short8*)&Bb[(nh      + n_) * 72 + kc * 32 + quad * 8];
            short8 b1 = *(const short8*)&Bb[(nh + 16 + n_) * 72 + kc * 32 + quad * 8];
            acc[0][0] = MFMA(a0, b0, acc[0][0]);
            acc[0][1] = MFMA(a0, b1, acc[0][1]);
            acc[1][0] = MFMA(a1, b0, acc[1][0]);
            acc[1][1] = MFMA(a1, b1, acc[1][1]);
        }
        if (more) {
            buf ^= 1;
            unsigned short* Aw = As + buf * 4608 + swoff;
            unsigned short* Bw = Bs + buf * 4608 + swoff;
            *(short8*)Aw = av0; *(short8*)(Aw + 8) = av1;
            *(short8*)Bw = bv0; *(short8*)(Bw + 8) = bv1;
            __syncthreads();
        }
    }

#pragma unroll
    for (int i = 0; i < 2; i++) {
#pragma unroll
        for (int j = 0; j < 2; j++) {
            const int mb = m0 + mh + i * 16 + quad * 4;
            const int nb = n0 + nh + j * 16 + n_;
            const float bsv = bias[nb];
#pragma unroll
            for (int reg = 0; reg < 4; reg++) {
                const int m = mb + reg;
                float v = acc[i][j][reg] + bsv;
                if (EPI == EPI_GELU) {
                    v = 0.5f * v * (1.0f + erff(v * 0.70710678118654752f));
                    Cb[(size_t)m * N + nb] = f2bf(v);
                } else if (EPI == EPI_BIAS) {
                    Cb[(size_t)m * N + nb] = f2bf(v);
                } else if (EPI == EPI_AMP) {
                    float u = (v > 20.f) ? v : log1pf(expf(v));
                    Cf[(size_t)m * N + nb] = u + 0.1f;
                } else if (EPI == EPI_PHASE) {
                    float am = extra[(size_t)m * 64 + nb];
                    float p = tanhf(v) * 3.14159265358979323846f;
                    float sp, cp; sincosf(p, &sp, &cp);
                    Cb[(size_t)m * 128 + nb]      = f2bf(am * cp);
                    Cb[(size_t)m * 128 + 64 + nb] = f2bf(am * sp);
                } else { // EPI_OUT
                    Cf[(size_t)m * N + nb] = v + extra[(size_t)m * N + nb];
                }
            }
        }
    }
}

// ---------- prep: weight transpose+cast (z<7) and x cast (z=7) ----------
__global__ __launch_bounds__(256)
void prep_k(const float* x, unsigned short* xb,
            const float* s0, const float* s1, const float* s2, const float* s3,
            const float* s4, const float* s5, const float* s6,
            unsigned short* d0, unsigned short* d1, unsigned short* d2, unsigned short* d3,
            unsigned short* d4, unsigned short* d5, unsigned short* d6)
{
    const int t = threadIdx.x;
    if (blockIdx.z == 7) {
        const int b = blockIdx.y * 16 + blockIdx.x;       // 0..255
        const float4* src = (const float4*)x;
#pragma unroll
        for (int j = 0; j < 4; j++) {
            const int idx = b * 1024 + j * 256 + t;
            float4 v = src[idx];
            us4 o;
            o.x = f2bf(v.x); o.y = f2bf(v.y); o.z = f2bf(v.z); o.w = f2bf(v.w);
            *(us4*)&xb[(size_t)idx * 4] = o;
        }
        return;
    }
    const float* S; unsigned short* D; int C;
    switch (blockIdx.z) {
        case 0: S = s0; D = d0; C = 512; break;
        case 1: S = s1; D = d1; C = 512; break;
        case 2: S = s2; D = d2; C = 512; break;
        case 3: S = s3; D = d3; C = 512; break;
        case 4: S = s4; D = d4; C = 64;  break;
        case 5: S = s5; D = d5; C = 64;  break;
        default: S = s6; D = d6; C = 64; break;
    }
    const int R = 512;
    int c0 = blockIdx.x * 32, r0 = blockIdx.y * 32;
    if (c0 >= C) return;
    __shared__ float tile[32][33];
    int r = t >> 3, c4 = (t & 7) * 4;
    float4 v = *(const float4*)&S[(size_t)(r0 + r) * C + c0 + c4];
    tile[r][c4 + 0] = v.x; tile[r][c4 + 1] = v.y;
    tile[r][c4 + 2] = v.z; tile[r][c4 + 3] = v.w;
    __syncthreads();
    us4 o;
    o.x = f2bf(tile[c4 + 0][r]); o.y = f2bf(tile[c4 + 1][r]);
    o.z = f2bf(tile[c4 + 2][r]); o.w = f2bf(tile[c4 + 3][r]);
    *(us4*)&D[(size_t)(c0 + r) * R + r0 + c4] = o;
}

// ---------- fused ke1+qe1+v+amp GEMMs (all read xb) ----------
__global__ __launch_bounds__(256)
void qkva_k(const unsigned short* __restrict__ xb,
            const unsigned short* wtke1, const unsigned short* wtqe1,
            const unsigned short* wtv, const unsigned short* wtamp,
            const float* ke_b1, const float* qe_b1, const float* v_b, const float* amp_b,
            unsigned short* hk, unsigned short* hq, unsigned short* Vb, float* amp)
{
    __shared__ unsigned short As[2 * 4608];
    __shared__ unsigned short Bs[2 * 4608];
    const int b = blockIdx.x;
    if (b < 768) {
        const int which = b >> 8, wi = b & 255;
        const int m0 = (wi >> 3) * 64, n0 = (wi & 7) * 64;
        if (which == 0)
            gemm_body<EPI_GELU>(xb, wtke1, ke_b1, 512, 512, m0, n0, hk, nullptr, nullptr, As, Bs);
        else if (which == 1)
            gemm_body<EPI_GELU>(xb, wtqe1, qe_b1, 512, 512, m0, n0, hq, nullptr, nullptr, As, Bs);
        else
            gemm_body<EPI_BIAS>(xb, wtv, v_b, 512, 512, m0, n0, Vb, nullptr, nullptr, As, Bs);
    } else {
        const int m0 = (b - 768) * 64;
        gemm_body<EPI_AMP>(xb, wtamp, amp_b, 64, 512, m0, 0, nullptr, amp, nullptr, As, Bs);
    }
}

// ---------- fused phase GEMMs + V transpose ----------
__global__ __launch_bounds__(256)
void phtv_k(const unsigned short* __restrict__ hk, const unsigned short* __restrict__ hq,
            const unsigned short* wtke2, const unsigned short* wtqe2,
            const float* ke_b2, const float* qe_b2, const float* ampv,
            unsigned short* Kp, unsigned short* Qp,
            const unsigned short* __restrict__ Vb, unsigned short* __restrict__ Vt)
{
    __shared__ unsigned short As[2 * 4608];
    __shared__ unsigned short Bs[2 * 4608];
    const int b = blockIdx.x;
    if (b < 64) {
        const int m0 = (b & 31) * 64;
        if (b < 32)
            gemm_body<EPI_PHASE>(hk, wtke2, ke_b2, 64, 512, m0, 0, Kp, nullptr, ampv, As, Bs);
        else
            gemm_body<EPI_PHASE>(hq, wtqe2, qe_b2, 64, 512, m0, 0, Qp, nullptr, ampv, As, Bs);
    } else {
        const int bb = b - 64;
        const int c0 = (bb & 15) * 32, r0 = (bb >> 4) * 32;
        unsigned short (*tile)[33] = (unsigned short (*)[33])As;
        const int t = threadIdx.x, r = t >> 3, c4 = (t & 7) * 4;
        us4 v = *(const us4*)&Vb[(size_t)(r0 + r) * 512 + c0 + c4];
        tile[r][c4 + 0] = v.x; tile[r][c4 + 1] = v.y;
        tile[r][c4 + 2] = v.z; tile[r][c4 + 3] = v.w;
        __syncthreads();
        us4 o;
        o.x = tile[c4 + 0][r]; o.y = tile[c4 + 1][r];
        o.z = tile[c4 + 2][r]; o.w = tile[c4 + 3][r];
        *(us4*)&Vt[(size_t)(c0 + r) * 2048 + r0 + c4] = o;
    }
}

// ---------- MFMA causal attention, bf16 partials ----------
__global__ __launch_bounds__(256)
void attm_k(const unsigned short* __restrict__ Qp, const unsigned short* __restrict__ Kp,
            const unsigned short* __restrict__ Vt, unsigned short* __restrict__ P, int ng)
{
    __shared__ unsigned short Ss[32 * 56];

    const int t = threadIdx.x;
    const int g = blockIdx.x, lt = blockIdx.y;
    const int l0 = lt * 32;
    const int w = t >> 6, lane = t & 63, n_ = lane & 15, quad = lane >> 4;
    const int lh = (w >> 1) * 16, th = (w & 1) * 16;

    short8 qf[4];
    {
        const unsigned short* qrow = &Qp[(size_t)(l0 + lh + n_) * 128 + quad * 8];
#pragma unroll
        for (int kc = 0; kc < 4; kc++) qf[kc] = *(const short8*)(qrow + kc * 32);
    }

    f32x4 acc[2][8];
#pragma unroll
    for (int i = 0; i < 2; i++)
#pragma unroll
        for (int j = 0; j < 8; j++) acc[i][j] = (f32x4){0.f, 0.f, 0.f, 0.f};

    for (int tile = g; tile <= lt; tile += ng) {
        const int t0 = tile * 32;
        const unsigned short* krow = &Kp[(size_t)(t0 + th + n_) * 128 + quad * 8];
        f32x4 s = (f32x4){0.f, 0.f, 0.f, 0.f};
#pragma unroll
        for (int kc = 0; kc < 4; kc++)
            s = MFMA(qf[kc], *(const short8*)(krow + kc * 32), s);

        const int lrow = lh + quad * 4;
        if (tile == lt) {
            const int tg = t0 + th + n_;
#pragma unroll
            for (int reg = 0; reg < 4; reg++) {
                float v = (tg <= l0 + lrow + reg) ? s[reg] : 0.f;
                Ss[(lrow + reg) * 56 + th + n_] = f2bf(v);
            }
        } else {
#pragma unroll
            for (int reg = 0; reg < 4; reg++)
                Ss[(lrow + reg) * 56 + th + n_] = f2bf(s[reg]);
        }
        __syncthreads();

        short8 sa0 = *(const short8*)&Ss[n_ * 56 + quad * 8];
        short8 sa1 = *(const short8*)&Ss[(16 + n_) * 56 + quad * 8];
        const unsigned short* vrow = &Vt[(size_t)(w * 128 + n_) * 2048 + t0 + quad * 8];
#pragma unroll
        for (int jc = 0; jc < 8; jc++) {
            short8 vf = *(const short8*)(vrow + (size_t)jc * 16 * 2048);
            acc[0][jc] = MFMA(sa0, vf, acc[0][jc]);
            acc[1][jc] = MFMA(sa1, vf, acc[1][jc]);
        }
        __syncthreads();
    }

    unsigned short* Pg = &P[((size_t)g * L_ + l0) * 512];
#pragma unroll
    for (int i = 0; i < 2; i++) {
#pragma unroll
        for (int jc = 0; jc < 8; jc++) {
            const int row = i * 16 + quad * 4;
            const int d = w * 128 + jc * 16 + n_;
#pragma unroll
            for (int reg = 0; reg < 4; reg++)
                Pg[(size_t)(row + reg) * 512 + d] = f2bf(acc[i][jc][reg]);
        }
    }
}

// ---------- reduce partials (bf16), scale, LayerNorm -> rn (bf16) ----------
__global__ __launch_bounds__(256)
void redln_k(const unsigned short* __restrict__ P, int ng,
             const float* __restrict__ lng, const float* __restrict__ lnb,
             unsigned short* __restrict__ rnb)
{
    const int l = blockIdx.x, t = threadIdx.x;
    float rx = 0.f, ry = 0.f;
    for (int gi = 0; gi < ng; gi++) {
        unsigned int p = *(const unsigned int*)&P[((size_t)gi * L_ + l) * 512 + 2 * t];
        rx += bf2f(p & 0xffffu);
        ry += bf2f(p >> 16);
    }
    const float scale = rsqrtf((float)((l + 1) * K_));
    rx *= scale; ry *= scale;

    float s = rx + ry, s2 = rx * rx + ry * ry;
    __shared__ float sb[8];
#pragma unroll
    for (int o = 32; o > 0; o >>= 1) {
        s  += __shfl_down(s,  o);
        s2 += __shfl_down(s2, o);
    }
    if ((t & 63) == 0) { int wv = t >> 6; sb[wv] = s; sb[4 + wv] = s2; }
    __syncthreads();
    s  = sb[0] + sb[1] + sb[2] + sb[3];
    s2 = sb[4] + sb[5] + sb[6] + sb[7];

    const float mu   = s * (1.f / 512.f);
    const float var  = s2 * (1.f / 512.f) - mu * mu;
    const float rstd = rsqrtf(var + 1e-5f);

    const int d = t << 1;
    rnb[(size_t)l * 512 + d]     = f2bf((rx - mu) * rstd * lng[d]     + lnb[d]);
    rnb[(size_t)l * 512 + d + 1] = f2bf((ry - mu) * rstd * lng[d + 1] + lnb[d + 1]);
}

// ---------- final out GEMM ----------
__global__ __launch_bounds__(256)
void outg_k(const unsigned short* __restrict__ rnb, const unsigned short* wtout,
            const float* out_b, const float* __restrict__ x, float* __restrict__ out)
{
    __shared__ unsigned short As[2 * 4608];
    __shared__ unsigned short Bs[2 * 4608];
    const int wi = blockIdx.x;
    const int m0 = (wi >> 3) * 64, n0 = (wi & 7) * 64;
    gemm_body<EPI_OUT>(rnb, wtout, out_b, 512, 512, m0, n0, nullptr, out, x, As, Bs);
}

extern "C" void kernel_launch(void* const* d_in, const int* in_sizes, int n_in,
                              void* d_out, int out_size, void* d_ws, size_t ws_size,
                              hipStream_t stream)
{
    const float* x     = (const float*)d_in[0];
    const float* ke_w1 = (const float*)d_in[1];
    const float* ke_b1 = (const float*)d_in[2];
    const float* ke_w2 = (const float*)d_in[3];
    const float* ke_b2 = (const float*)d_in[4];
    const float* qe_w1 = (const float*)d_in[5];
    const float* qe_b1 = (const float*)d_in[6];
    const float* qe_w2 = (const float*)d_in[7];
    const float* qe_b2 = (const float*)d_in[8];
    const float* amp_w = (const float*)d_in[9];
    const float* amp_b = (const float*)d_in[10];
    const float* v_w   = (const float*)d_in[11];
    const float* v_b   = (const float*)d_in[12];
    const float* ln_g  = (const float*)d_in[13];
    const float* ln_b  = (const float*)d_in[14];
    const float* out_w = (const float*)d_in[15];
    const float* out_b = (const float*)d_in[16];
    float* out = (float*)d_out;
    char*  wsb = (char*)d_ws;

    unsigned short* xb    = (unsigned short*)(wsb + 0);          // 2 MB
    unsigned short* hk    = (unsigned short*)(wsb + 2097152);    // 2 MB
    unsigned short* hq    = (unsigned short*)(wsb + 4194304);    // 2 MB
    unsigned short* Vb    = (unsigned short*)(wsb + 6291456);    // 2 MB
    unsigned short* Vt    = (unsigned short*)(wsb + 8388608);    // 2 MB
    unsigned short* Qp    = (unsigned short*)(wsb + 10485760);   // 0.5 MB
    unsigned short* Kp    = (unsigned short*)(wsb + 11010048);   // 0.5 MB
    float*          amp   = (float*)(wsb + 11534336);            // 0.5 MB
    unsigned short* rnb   = (unsigned short*)(wsb + 12058624);   // 2 MB
    unsigned short* wtke1 = (unsigned short*)(wsb + 14155776);
    unsigned short* wtqe1 = (unsigned short*)(wsb + 14680064);
    unsigned short* wtv   = (unsigned short*)(wsb + 15204352);
    unsigned short* wtout = (unsigned short*)(wsb + 15728640);
    unsigned short* wtke2 = (unsigned short*)(wsb + 16252928);
    unsigned short* wtqe2 = (unsigned short*)(wsb + 16318464);
    unsigned short* wtamp = (unsigned short*)(wsb + 16384000);
    unsigned short* P     = (unsigned short*)(wsb + 16449536);   // ng * 2 MB (bf16)

    const size_t base_bytes = 16449536ull;
    const size_t per_group  = 2097152ull;
    int ng = 1;
    if (ws_size > base_bytes + per_group) {
        size_t n = (ws_size - base_bytes) / per_group;
        ng = (n > 8) ? 8 : (int)n;
        if (ng < 1) ng = 1;
    }

    dim3 blk(256);
    prep_k<<<dim3(16, 16, 8), blk, 0, stream>>>(x, xb,
                                                ke_w1, qe_w1, v_w, out_w, ke_w2, qe_w2, amp_w,
                                                wtke1, wtqe1, wtv, wtout, wtke2, wtqe2, wtamp);
    qkva_k<<<dim3(800), blk, 0, stream>>>(xb, wtke1, wtqe1, wtv, wtamp,
                                          ke_b1, qe_b1, v_b, amp_b, hk, hq, Vb, amp);
    phtv_k<<<dim3(1088), blk, 0, stream>>>(hk, hq, wtke2, wtqe2, ke_b2, qe_b2, amp,
                                           Kp, Qp, Vb, Vt);
    attm_k<<<dim3(ng, 64), blk, 0, stream>>>(Qp, Kp, Vt, P, ng);
    redln_k<<<dim3(L_), blk, 0, stream>>>(P, ng, ln_g, ln_b, rnb);
    outg_k<<<dim3(256), blk, 0, stream>>>(rnb, wtout, out_b, x, out);
}